// Round 9
// baseline (1684.994 us; speedup 1.0000x reference)
//
#include <hip/hip_runtime.h>

#define N_ATOMS 131072
#define M_NBR 12
#define ORIG_F 92
#define AF 64
#define NCONV 3
#define N0_CRYS 1024
#define FIN 169
#define C2 128
#define KPAD 192
#define BN_EPS 1e-5f
#define RB_TOTAL (N_ATOMS * M_NBR / 64)   // 24576 row-blocks of 64 (gemmA)
#define BT_TOTAL (N_ATOMS * M_NBR / 96)   // 16384 row-blocks of 96 (gemmB)

typedef _Float16 f16;
typedef _Float16 half8 __attribute__((ext_vector_type(8)));
typedef float f32x4 __attribute__((ext_vector_type(4)));

union H8 { half8 h; ushort4 u[2]; };

// Native-rate transcendentals (v_exp_f32 = 2^x, v_log_f32 = log2, v_rcp_f32).
__device__ __forceinline__ float fexp_(float t) {   // e^t
    float r; asm("v_exp_f32 %0, %1" : "=v"(r) : "v"(t * 1.44269504f)); return r;
}
__device__ __forceinline__ float flog_(float t) {   // ln t
    float r; asm("v_log_f32 %0, %1" : "=v"(r) : "v"(t)); return r * 0.69314718f;
}
__device__ __forceinline__ float frcp_(float t) {
    float r; asm("v_rcp_f32 %0, %1" : "=v"(r) : "v"(t)); return r;
}
__device__ __forceinline__ float sigmoidf_(float t) {
    return frcp_(1.0f + fexp_(-t));
}
__device__ __forceinline__ float softplusf_(float t) {
    return fmaxf(t, 0.0f) + flog_(1.0f + fexp_(-fabsf(t)));
}

// ---------------- pre: fused embed + cvt_nbrf + prepW(layer 0) --------------
// Role split by blockIdx (uniform per block, no intra-block divergence):
//   [0, 1024)        embed: x = af @ W_embed + b (LDS-staged W, fp32-exact)
//   [1024, 4096)     cvt: nbr_fea -> f16 padded [N*M][44]
//   [4096, 4192)     prepW for layer 0
__global__ __launch_bounds__(256) void k_pre(const float* __restrict__ af,
                                             const float* __restrict__ We,
                                             const float* __restrict__ be,
                                             float* __restrict__ x,
                                             f16* __restrict__ xh,
                                             const float* __restrict__ nf,
                                             f16* __restrict__ nfh,
                                             const float* __restrict__ Wc0,
                                             f16* __restrict__ Wt) {
    const int tid = threadIdx.x;
    if (blockIdx.x < 1024) {
        __shared__ float Wl[ORIG_F * AF];   // 23552 B
        for (int i = tid; i < ORIG_F * AF / 4; i += 256)
            *(f32x4*)&Wl[i * 4] = *(const f32x4*)&We[i * 4];
        __syncthreads();

        const int a = tid >> 4;            // atom slot 0..15
        const int f0 = (tid & 15) * 4;     // output features f0..f0+3
        const f32x4 bias = *(const f32x4*)&be[f0];
#pragma unroll
        for (int ch = 0; ch < 8; ++ch) {
            const int n = blockIdx.x * 128 + ch * 16 + a;
            const float* ar = af + (size_t)n * ORIG_F;
            f32x4 acc = bias;
            for (int k4 = 0; k4 < 23; ++k4) {
                f32x4 av = *(const f32x4*)&ar[k4 * 4];
#pragma unroll
                for (int e = 0; e < 4; ++e) {
                    f32x4 wv = *(const f32x4*)&Wl[(k4 * 4 + e) * AF + f0];
#pragma unroll
                    for (int j = 0; j < 4; ++j)
                        acc[j] = fmaf(av[e], wv[j], acc[j]);
                }
            }
            *(f32x4*)&x[(size_t)n * AF + f0] = acc;
            f16 h4[4] = {(f16)acc[0], (f16)acc[1], (f16)acc[2], (f16)acc[3]};
            *(ushort4*)&xh[(size_t)n * AF + f0] = *(const ushort4*)h4;
        }
    } else if (blockIdx.x < 4096) {
        const int bid = blockIdx.x - 1024;                 // 3072 blocks
        for (int chunk = bid; chunk < N_ATOMS * M_NBR / 32; chunk += 3072) {
            const int r0 = chunk * 32;
            for (int i = tid; i < 32 * 22; i += 256) {
                int r = i / 22, k2 = i - r * 22;
                size_t row = (size_t)(r0 + r);
                int k = k2 * 2;
                float f0 = (k < 41) ? nf[row * 41 + k] : 0.0f;
                float f1 = (k + 1 < 41) ? nf[row * 41 + k + 1] : 0.0f;
                f16 two[2] = {(f16)f0, (f16)f1};
                *(ushort2*)&nfh[row * 44 + k] = *(const ushort2*)two;
            }
        }
    } else {
        const int i = (blockIdx.x - 4096) * 256 + tid;     // 96 blocks
        if (i < C2 * KPAD) {
            int c = i / KPAD, k = i - c * KPAD;
            Wt[i] = (k < FIN) ? (f16)Wc0[k * C2 + c] : (f16)0.0f;
        }
    }
}

// ---------------- gemmA: MFMA gemm, BN1 stats ONLY (no gated store) ----------
// 64-row tile, 4 waves (2 row-half x 2 col-half), direct-from-global A
// fragments via 32-bit byte offsets, no in-loop barriers. nidx for the NEXT
// iteration is prefetched at loop top so the gather chain (nidx -> addr ->
// gather) is off the critical path. Bias deferred from stats (closed form).
__global__ __launch_bounds__(256) void k_gemmA(const f16* __restrict__ xh,
                                               const f16* __restrict__ nfh,
                                               const int* __restrict__ nidx,
                                               const f16* __restrict__ Wt,
                                               const float* __restrict__ bl,
                                               float* __restrict__ stats) {
    __shared__ float redS[128], redQ[128];

    const int tid = threadIdx.x;
    const int wv = tid >> 6;
    const int lane = tid & 63;
    const int quad = lane >> 4;
    const int l16 = lane & 15;
    const int rhalf = wv >> 1;
    const int c0w = (wv & 1) * 64;
    const unsigned q16 = (unsigned)quad * 16u;

    if (tid < 128) { redS[tid] = 0.0f; redQ[tid] = 0.0f; }

    half8 Bf[6][4];
    float bias_[4];
    float ssum[4] = {0, 0, 0, 0}, ssq[4] = {0, 0, 0, 0};
    int niter = 0;
#pragma unroll
    for (int ct = 0; ct < 4; ++ct) {
        int c = c0w + ct * 16 + l16;
        bias_[ct] = bl[c];
#pragma unroll
        for (int kc = 0; kc < 6; ++kc)
            Bf[kc][ct] = *(const half8*)&Wt[c * KPAD + kc * 32 + quad * 8];
    }

    const char* xb = (const char*)xh;
    const char* nb = (const char*)nfh;
    const ushort4 z4 = make_ushort4(0, 0, 0, 0);

    // prefetch first iteration's neighbor indices
    int ng0 = 0, ng1 = 0;
    {
        const int row0 = blockIdx.x * 64 + rhalf * 32 + l16;
        ng0 = nidx[row0];
        ng1 = nidx[row0 + 16];
    }

    for (int rb = blockIdx.x; rb < RB_TOTAL; rb += gridDim.x) {
        // issue next-iter nidx loads NOW (result needed only next iteration)
        const int rbn = rb + gridDim.x;
        int ng0n = 0, ng1n = 0;
        if (rbn < RB_TOTAL) {
            const int rown = rbn * 64 + rhalf * 32 + l16;
            ng0n = nidx[rown];
            ng1n = nidx[rown + 16];
        }

        const int row0 = rb * 64 + rhalf * 32 + l16;
        const int row1 = row0 + 16;
        const unsigned os0 = (unsigned)((unsigned)row0 / 12u) * 128u + q16;
        const unsigned os1 = (unsigned)((unsigned)row1 / 12u) * 128u + q16;
        const unsigned og0 = (unsigned)ng0 * 128u + q16;
        const unsigned og1 = (unsigned)ng1 * 128u + q16;
        const unsigned on0 = (unsigned)row0 * 88u;
        const unsigned on1 = (unsigned)row1 * 88u;

        H8 a0[6], a1[6];
        a0[0].h = *(const half8*)(xb + os0);
        a0[1].h = *(const half8*)(xb + os0 + 64u);
        a0[2].h = *(const half8*)(xb + og0);
        a0[3].h = *(const half8*)(xb + og0 + 64u);
        a0[4].u[0] = *(const ushort4*)(nb + on0 + q16);
        a0[4].u[1] = *(const ushort4*)(nb + on0 + q16 + 8u);
        a0[5].u[0] = z4; a0[5].u[1] = z4;
        if (quad == 0) {
            a0[5].u[0] = *(const ushort4*)(nb + on0 + 64u);
            a0[5].u[1] = *(const ushort4*)(nb + on0 + 72u);
        } else if (quad == 1) {
            a0[5].u[0] = *(const ushort4*)(nb + on0 + 80u);
        }
        a1[0].h = *(const half8*)(xb + os1);
        a1[1].h = *(const half8*)(xb + os1 + 64u);
        a1[2].h = *(const half8*)(xb + og1);
        a1[3].h = *(const half8*)(xb + og1 + 64u);
        a1[4].u[0] = *(const ushort4*)(nb + on1 + q16);
        a1[4].u[1] = *(const ushort4*)(nb + on1 + q16 + 8u);
        a1[5].u[0] = z4; a1[5].u[1] = z4;
        if (quad == 0) {
            a1[5].u[0] = *(const ushort4*)(nb + on1 + 64u);
            a1[5].u[1] = *(const ushort4*)(nb + on1 + 72u);
        } else if (quad == 1) {
            a1[5].u[0] = *(const ushort4*)(nb + on1 + 80u);
        }

        f32x4 acc[2][4];
#pragma unroll
        for (int rf = 0; rf < 2; ++rf)
#pragma unroll
            for (int ct = 0; ct < 4; ++ct) acc[rf][ct] = (f32x4){0, 0, 0, 0};

#pragma unroll
        for (int kc = 0; kc < 6; ++kc) {
#pragma unroll
            for (int ct = 0; ct < 4; ++ct) {
                acc[0][ct] = __builtin_amdgcn_mfma_f32_16x16x32_f16(a0[kc].h, Bf[kc][ct], acc[0][ct], 0, 0, 0);
                acc[1][ct] = __builtin_amdgcn_mfma_f32_16x16x32_f16(a1[kc].h, Bf[kc][ct], acc[1][ct], 0, 0, 0);
            }
        }

        // stats-only epilogue (bias deferred)
#pragma unroll
        for (int rf = 0; rf < 2; ++rf)
#pragma unroll
            for (int ct = 0; ct < 4; ++ct)
#pragma unroll
                for (int e = 0; e < 4; ++e) {
                    float v = acc[rf][ct][e];
                    ssum[ct] += v;
                    ssq[ct] = fmaf(v, v, ssq[ct]);
                }
        ++niter;
        ng0 = ng0n; ng1 = ng1n;
    }

    // fold the deferred bias: sum(v+b) = S + cnt*b ; sum((v+b)^2) = Q + 2bS + cnt*b^2
    const float cnt = 8.0f * (float)niter;   // 8 values per ct per iteration
#pragma unroll
    for (int ct = 0; ct < 4; ++ct) {
        float b = bias_[ct];
        float S = ssum[ct];
        ssq[ct] = ssq[ct] + 2.0f * b * S + cnt * b * b;
        ssum[ct] = S + cnt * b;
    }

    __syncthreads();   // makes redS/redQ zero-init visible
#pragma unroll
    for (int ct = 0; ct < 4; ++ct) {
        float s = ssum[ct], q = ssq[ct];
        s += __shfl_xor(s, 16); s += __shfl_xor(s, 32);
        q += __shfl_xor(q, 16); q += __shfl_xor(q, 32);
        if (quad == 0) {
            atomicAdd(&redS[c0w + ct * 16 + l16], s);
            atomicAdd(&redQ[c0w + ct * 16 + l16], q);
        }
    }
    __syncthreads();
    if (tid < 128) {
        atomicAdd(&stats[tid], redS[tid]);
        atomicAdd(&stats[128 + tid], redQ[tid]);
    }
}

// ---------------- gemmB: recompute gemm + BN1 + sigmoid*softplus + atom-sum --
// Block = 256 thr (4 waves) x 96 rows (8 atoms). Wave w: rows (w>>1)*48..+47
// (4 atoms), cols = tiles {2s,2s+1,4+2s,5+2s} (s=w&1) so filter col c and
// core col c+64 are in the SAME lane. Atom-sum via per-WAVE LDS scratch
// (intra-wave: lgkmcnt-ordered, no barriers in the loop). nidx prefetched
// one iteration ahead.
__global__ __launch_bounds__(256) void k_gemmB(const f16* __restrict__ xh,
                                               const f16* __restrict__ nfh,
                                               const int* __restrict__ nidx,
                                               const f16* __restrict__ Wt,
                                               const float* __restrict__ bl,
                                               const float* __restrict__ g1,
                                               const float* __restrict__ be1,
                                               float* __restrict__ stats,
                                               float* __restrict__ ns) {
    __shared__ float scr[4][12][33];   // [wave][4-row group][col] (+pad)
    __shared__ float rs[64], rq[64];

    const int tid = threadIdx.x;
    const int wv = tid >> 6;
    const int lane = tid & 63;
    const int quad = lane >> 4;
    const int l16 = lane & 15;
    const int rgrp = wv >> 1;          // row group 0/1 (48 rows each)
    const int csel = wv & 1;           // column half of the 64 product cols
    const unsigned q16 = (unsigned)quad * 16u;
    const float cnt1 = (float)N_ATOMS * M_NBR;

    if (tid < 64) { rs[tid] = 0.0f; rq[tid] = 0.0f; }
    __syncthreads();

    const int tmap[4] = {2 * csel, 2 * csel + 1, 4 + 2 * csel, 5 + 2 * csel};
    float P[4], Q[4];
    half8 Bf[4][6];
#pragma unroll
    for (int jt = 0; jt < 4; ++jt) {
        int c = tmap[jt] * 16 + l16;
        float m1 = stats[c] / cnt1;
        float v1 = stats[128 + c] / cnt1 - m1 * m1;
        float A1 = g1[c] * rsqrtf(v1 + BN_EPS);
        P[jt] = A1;
        Q[jt] = fmaf(A1, bl[c], be1[c] - A1 * m1);   // BN1 with gemm-bias folded in
#pragma unroll
        for (int kc = 0; kc < 6; ++kc)
            Bf[jt][kc] = *(const half8*)&Wt[c * KPAD + kc * 32 + quad * 8];
    }

    const char* xb = (const char*)xh;
    const char* nb = (const char*)nfh;
    const ushort4 z4 = make_ushort4(0, 0, 0, 0);
    float ls[2] = {0, 0}, lq2[2] = {0, 0};

    // prefetch first iteration's neighbor indices
    int ng[3];
    {
        const int rw = blockIdx.x * 96 + rgrp * 48;
#pragma unroll
        for (int rt = 0; rt < 3; ++rt) ng[rt] = nidx[rw + rt * 16 + l16];
    }

    for (int bt = blockIdx.x; bt < BT_TOTAL; bt += gridDim.x) {
        // issue next-iter nidx loads NOW
        const int btn = bt + gridDim.x;
        int ngn[3] = {0, 0, 0};
        if (btn < BT_TOTAL) {
            const int rwn = btn * 96 + rgrp * 48;
#pragma unroll
            for (int rt = 0; rt < 3; ++rt) ngn[rt] = nidx[rwn + rt * 16 + l16];
        }

        const int rw = bt * 96 + rgrp * 48;
        float part[3][2];
#pragma unroll
        for (int rt = 0; rt < 3; ++rt) {
            const int r = rw + rt * 16 + l16;
            const unsigned osf = (unsigned)((unsigned)r / 12u) * 128u + q16;
            const unsigned ogf = (unsigned)ng[rt] * 128u + q16;
            const unsigned onf = (unsigned)r * 88u;
            H8 a[6];
            a[0].h = *(const half8*)(xb + osf);
            a[1].h = *(const half8*)(xb + osf + 64u);
            a[2].h = *(const half8*)(xb + ogf);
            a[3].h = *(const half8*)(xb + ogf + 64u);
            a[4].u[0] = *(const ushort4*)(nb + onf + q16);
            a[4].u[1] = *(const ushort4*)(nb + onf + q16 + 8u);
            a[5].u[0] = z4; a[5].u[1] = z4;
            if (quad == 0) {
                a[5].u[0] = *(const ushort4*)(nb + onf + 64u);
                a[5].u[1] = *(const ushort4*)(nb + onf + 72u);
            } else if (quad == 1) {
                a[5].u[0] = *(const ushort4*)(nb + onf + 80u);
            }

            f32x4 acc[4];
#pragma unroll
            for (int jt = 0; jt < 4; ++jt) acc[jt] = (f32x4){0, 0, 0, 0};
#pragma unroll
            for (int kc = 0; kc < 6; ++kc)
#pragma unroll
                for (int jt = 0; jt < 4; ++jt)
                    acc[jt] = __builtin_amdgcn_mfma_f32_16x16x32_f16(a[kc].h, Bf[jt][kc], acc[jt], 0, 0, 0);

            // C layout: row = rw + rt*16 + quad*4 + e, col = tmap[jt]*16 + l16
#pragma unroll
            for (int j = 0; j < 2; ++j) {
                float s = 0.0f;
#pragma unroll
                for (int e = 0; e < 4; ++e) {
                    float vf = fmaf(P[j],     acc[j][e],     Q[j]);       // filter col
                    float vc = fmaf(P[j + 2], acc[j + 2][e], Q[j + 2]);   // core col (+64)
                    s = fmaf(sigmoidf_(vf), softplusf_(vc), s);
                }
                part[rt][j] = s;   // sum over rows of group g = rt*4+quad
            }
        }
        // intra-wave exchange (no barrier): group g partial lives in lane
        // (g&3)*16+l16 of the same wave, register part[g>>2].
#pragma unroll
        for (int rt = 0; rt < 3; ++rt)
#pragma unroll
            for (int j = 0; j < 2; ++j)
                scr[wv][rt * 4 + quad][j * 16 + l16] = part[rt][j];
        // atom a = quad (4 atoms/wave); its 12 rows = groups 3a..3a+2
#pragma unroll
        for (int j = 0; j < 2; ++j) {
            int cj = j * 16 + l16;
            float s = scr[wv][3 * quad][cj] + scr[wv][3 * quad + 1][cj] + scr[wv][3 * quad + 2][cj];
            const int n = bt * 8 + rgrp * 4 + quad;
            ns[(size_t)n * 64 + csel * 32 + cj] = s;
            ls[j] += s;
            lq2[j] = fmaf(s, s, lq2[j]);
        }
        ng[0] = ngn[0]; ng[1] = ngn[1]; ng[2] = ngn[2];
    }

    // BN2 stats: per-lane col fixed (csel*32 + j*16 + l16); quads hold
    // disjoint atoms -> reduce across quads, then across waves via LDS+atomics.
#pragma unroll
    for (int j = 0; j < 2; ++j) {
        float s = ls[j], q = lq2[j];
        s += __shfl_xor(s, 16); s += __shfl_xor(s, 32);
        q += __shfl_xor(q, 16); q += __shfl_xor(q, 32);
        if (quad == 0) {
            atomicAdd(&rs[csel * 32 + j * 16 + l16], s);
            atomicAdd(&rq[csel * 32 + j * 16 + l16], q);
        }
    }
    __syncthreads();
    if (tid < 64) {
        atomicAdd(&stats[256 + tid], rs[tid]);
        atomicAdd(&stats[320 + tid], rq[tid]);
    }
}

// ---------------- convC (vectorized) + prepW(l+1) fused ----------------------
// Blocks [0, 8192): x = softplus(x + BN2(ns)), 4 elems/thread (f32x4).
// Blocks [8192, 8288): prepW for the next layer (gated by do_prep).
__global__ __launch_bounds__(256) void k_convC2(float* __restrict__ x,
                                                f16* __restrict__ xh,
                                                const float* __restrict__ ns,
                                                const float* __restrict__ g2,
                                                const float* __restrict__ be2,
                                                const float* __restrict__ stats,
                                                const float* __restrict__ Wn,
                                                f16* __restrict__ Wt,
                                                int do_prep) {
    const int tid = threadIdx.x;
    if (blockIdx.x < 8192) {
        const int i4 = blockIdx.x * 256 + tid;       // < N*64/4
        const size_t base = (size_t)i4 * 4;
        const int f0 = (int)(base & 63);
        const float cnt = (float)N_ATOMS;
        f32x4 m4 = *(const f32x4*)&stats[256 + f0];
        f32x4 q4 = *(const f32x4*)&stats[320 + f0];
        f32x4 g4 = *(const f32x4*)&g2[f0];
        f32x4 b4 = *(const f32x4*)&be2[f0];
        f32x4 xv = *(const f32x4*)&x[base];
        f32x4 nv = *(const f32x4*)&ns[base];
        f16 h4[4];
#pragma unroll
        for (int j = 0; j < 4; ++j) {
            float m = m4[j] / cnt;
            float v = q4[j] / cnt - m * m;
            float A = g4[j] * rsqrtf(v + BN_EPS);
            float B = b4[j] - A * m;
            float o = softplusf_(xv[j] + fmaf(A, nv[j], B));
            xv[j] = o;
            h4[j] = (f16)o;
        }
        *(f32x4*)&x[base] = xv;
        *(ushort4*)&xh[base] = *(const ushort4*)h4;
    } else if (do_prep) {
        const int i = (blockIdx.x - 8192) * 256 + tid;
        if (i < C2 * KPAD) {
            int c = i / KPAD, k = i - c * KPAD;
            Wt[i] = (k < FIN) ? (f16)Wn[k * C2 + c] : (f16)0.0f;
        }
    }
}

// ---------------- pool: per-crystal mean (sorted idx, binary search) ---------
__global__ __launch_bounds__(64) void k_pool(const float* __restrict__ x,
                                             const int* __restrict__ cidx,
                                             float* __restrict__ crys) {
    const int s = blockIdx.x;
    const int f = threadIdx.x;
    int lo = 0, hi = N_ATOMS;
    while (lo < hi) { int mid = (lo + hi) >> 1; if (cidx[mid] < s) lo = mid + 1; else hi = mid; }
    int lo2 = lo, hi2 = N_ATOMS;
    while (lo2 < hi2) { int mid = (lo2 + hi2) >> 1; if (cidx[mid] < s + 1) lo2 = mid + 1; else hi2 = mid; }
    float sum = 0.0f;
    for (int i = lo; i < lo2; ++i) sum += x[(size_t)i * 64 + f];
    float cnt = fmaxf((float)(lo2 - lo), 1.0f);
    crys[s * 64 + f] = sum / cnt;
}

// ---------------- head ----------------
__global__ __launch_bounds__(128) void k_head(const float* __restrict__ crys,
                                              const float* __restrict__ W1,
                                              const float* __restrict__ b1,
                                              const float* __restrict__ W2,
                                              const float* __restrict__ b2,
                                              float* __restrict__ out) {
    __shared__ float a_sh[64];
    __shared__ float r_sh[128];
    const int n = blockIdx.x;
    const int tid = threadIdx.x;
    if (tid < 64) a_sh[tid] = softplusf_(crys[n * 64 + tid]);
    __syncthreads();
    for (int p = 0; p < 2; ++p) {
        float acc = b1[p * 128 + tid];
#pragma unroll
        for (int f2 = 0; f2 < 64; ++f2)
            acc = fmaf(a_sh[f2], W1[(p * 64 + f2) * 128 + tid], acc);
        float contrib = softplusf_(acc) * W2[p * 128 + tid];
        r_sh[tid] = contrib;
        __syncthreads();
        for (int sft = 64; sft > 0; sft >>= 1) {
            if (tid < sft) r_sh[tid] += r_sh[tid + sft];
            __syncthreads();
        }
        if (tid == 0) out[n * 2 + p] = r_sh[0] + b2[p];
        __syncthreads();
    }
}

extern "C" void kernel_launch(void* const* d_in, const int* in_sizes, int n_in,
                              void* d_out, int out_size, void* d_ws, size_t ws_size,
                              hipStream_t stream) {
    const float* atom_fea = (const float*)d_in[0];
    const float* nbr_fea  = (const float*)d_in[1];
    const float* W_embed  = (const float*)d_in[2];
    const float* b_embed  = (const float*)d_in[3];
    const float* conv_W   = (const float*)d_in[4];
    const float* conv_b   = (const float*)d_in[5];
    const float* conv_g1  = (const float*)d_in[6];
    const float* conv_be1 = (const float*)d_in[7];
    const float* conv_g2  = (const float*)d_in[8];
    const float* conv_be2 = (const float*)d_in[9];
    const float* head_W1  = (const float*)d_in[10];
    const float* head_b1  = (const float*)d_in[11];
    const float* head_W2  = (const float*)d_in[12];
    const float* head_b2  = (const float*)d_in[13];
    const int*   nidx     = (const int*)d_in[14];
    const int*   cryst    = (const int*)d_in[15];

    // workspace layout (nfh 44-f16 stride)
    char* w = (char*)d_ws;
    float* x      = (float*)w;                        //  33,554,432
    f16*   xh     = (f16*)(w + 33554432);             //  16,777,216
    float* ns     = (float*)(w + 50331648);           //  33,554,432
    f16*   nfh    = (f16*)(w + 83886080);             // 138,412,032
    f16*   Wt     = (f16*)(w + 222298112);            //      49,152
    float* stats  = (float*)(w + 222347264);          //       4,608
    const size_t required = 222347264ull + 4608ull;
    if (ws_size < required) {
        hipMemsetAsync(d_out, 0x7F, 4, stream);
        return;
    }

    hipMemsetAsync(stats, 0, NCONV * 384 * sizeof(float), stream);

    // fused: embed + cvt_nbrf + prepW(0)
    k_pre<<<4192, 256, 0, stream>>>(atom_fea, W_embed, b_embed, x, xh,
                                    nbr_fea, nfh, conv_W, Wt);

    for (int l = 0; l < NCONV; ++l) {
        float* st = stats + l * 384;
        k_gemmA<<<2048, 256, 0, stream>>>(xh, nfh, nidx, Wt, conv_b + l * C2, st);
        k_gemmB<<<2048, 256, 0, stream>>>(xh, nfh, nidx, Wt, conv_b + l * C2,
                                          conv_g1 + l * C2, conv_be1 + l * C2, st, ns);
        const int ln = (l + 1 < NCONV) ? l + 1 : l;
        k_convC2<<<8288, 256, 0, stream>>>(x, xh, ns, conv_g2 + l * AF, conv_be2 + l * AF, st,
                                           conv_W + (size_t)ln * FIN * C2, Wt, (l + 1 < NCONV) ? 1 : 0);
    }

    float* crys = (float*)d_out + N0_CRYS * 2;   // crys_fea follows out
    k_pool<<<N0_CRYS, 64, 0, stream>>>(x, cryst, crys);
    k_head<<<N0_CRYS, 128, 0, stream>>>(crys, head_W1, head_b1, head_W2, head_b2, (float*)d_out);
}

// Round 10
// 1376.097 us; speedup vs baseline: 1.2245x; 1.2245x over previous
//
#include <hip/hip_runtime.h>

#define N_ATOMS 131072
#define M_NBR 12
#define ORIG_F 92
#define AF 64
#define NCONV 3
#define N0_CRYS 1024
#define FIN 169
#define C2 128
#define KPAD 192
#define BN_EPS 1e-5f
#define RB_TOTAL (N_ATOMS * M_NBR / 64)   // 24576 row-blocks of 64 (gemmA)
#define BT_TOTAL (N_ATOMS * M_NBR / 96)   // 16384 row-blocks of 96 (gemmB)

typedef _Float16 f16;
typedef _Float16 half8 __attribute__((ext_vector_type(8)));
typedef float f32x4 __attribute__((ext_vector_type(4)));

union H8 { half8 h; ushort4 u[2]; };

// Native-rate transcendentals (v_exp_f32 = 2^x, v_log_f32 = log2, v_rcp_f32).
__device__ __forceinline__ float fexp_(float t) {   // e^t
    float r; asm("v_exp_f32 %0, %1" : "=v"(r) : "v"(t * 1.44269504f)); return r;
}
__device__ __forceinline__ float flog_(float t) {   // ln t
    float r; asm("v_log_f32 %0, %1" : "=v"(r) : "v"(t)); return r * 0.69314718f;
}
__device__ __forceinline__ float frcp_(float t) {
    float r; asm("v_rcp_f32 %0, %1" : "=v"(r) : "v"(t)); return r;
}
__device__ __forceinline__ float sigmoidf_(float t) {
    return frcp_(1.0f + fexp_(-t));
}
__device__ __forceinline__ float softplusf_(float t) {
    return fmaxf(t, 0.0f) + flog_(1.0f + fexp_(-fabsf(t)));
}

// ---------------- embed: x = atom_fea @ W_embed + b  (fp32-exact, LDS W) -----
// STANDALONE (un-fused from k_pre: the 23.5KB LDS + 144 VGPR footprint must
// not be charged to the streaming cvt blocks -- round-9 fusion ran at 10.9%
// occupancy, 674 GB/s).
__global__ __launch_bounds__(256) void k_embed(const float* __restrict__ af,
                                               const float* __restrict__ W,
                                               const float* __restrict__ b,
                                               float* __restrict__ x,
                                               f16* __restrict__ xh) {
    __shared__ float Wl[ORIG_F * AF];   // 23552 B
    const int tid = threadIdx.x;
    for (int i = tid; i < ORIG_F * AF / 4; i += 256)
        *(f32x4*)&Wl[i * 4] = *(const f32x4*)&W[i * 4];
    __syncthreads();

    const int a = tid >> 4;            // atom slot 0..15
    const int f0 = (tid & 15) * 4;     // output features f0..f0+3
    const f32x4 bias = *(const f32x4*)&b[f0];

#pragma unroll
    for (int ch = 0; ch < 8; ++ch) {
        const int n = blockIdx.x * 128 + ch * 16 + a;
        const float* ar = af + (size_t)n * ORIG_F;
        f32x4 acc = bias;
        for (int k4 = 0; k4 < 23; ++k4) {          // 92 = 23*4, rows 16B-aligned
            f32x4 av = *(const f32x4*)&ar[k4 * 4];
#pragma unroll
            for (int e = 0; e < 4; ++e) {
                f32x4 wv = *(const f32x4*)&Wl[(k4 * 4 + e) * AF + f0];
#pragma unroll
                for (int j = 0; j < 4; ++j)
                    acc[j] = fmaf(av[e], wv[j], acc[j]);
            }
        }
        *(f32x4*)&x[(size_t)n * AF + f0] = acc;
        f16 h4[4] = {(f16)acc[0], (f16)acc[1], (f16)acc[2], (f16)acc[3]};
        *(ushort4*)&xh[(size_t)n * AF + f0] = *(const ushort4*)h4;
    }
}

// ---------------- cvt nbr_fea -> f16 padded [N*M][44], ushort2 stores --------
__global__ __launch_bounds__(256) void k_cvt_nbrf(const float* __restrict__ nf,
                                                  f16* __restrict__ nfh) {
    const int r0 = blockIdx.x * 32;
    for (int i = threadIdx.x; i < 32 * 22; i += 256) {
        int r = i / 22, k2 = i - r * 22;
        size_t row = (size_t)(r0 + r);
        int k = k2 * 2;
        float f0 = (k < 41) ? nf[row * 41 + k] : 0.0f;
        float f1 = (k + 1 < 41) ? nf[row * 41 + k + 1] : 0.0f;
        f16 two[2] = {(f16)f0, (f16)f1};
        *(ushort2*)&nfh[row * 44 + k] = *(const ushort2*)two;
    }
}

// ---------------- prep W^T: Wt[c][k] f16, k padded to 192 ----------------
__global__ __launch_bounds__(256) void k_prepW(const float* __restrict__ W,
                                               f16* __restrict__ Wt) {
    int i = blockIdx.x * 256 + threadIdx.x;    // i < 128*192
    if (i >= C2 * KPAD) return;
    int c = i / KPAD, k = i - c * KPAD;
    Wt[i] = (k < FIN) ? (f16)W[k * C2 + c] : (f16)0.0f;
}

// ---------------- gemmA: MFMA gemm, BN1 stats ONLY (no gated store) ----------
// 64-row tile, 4 waves (2 row-half x 2 col-half), direct-from-global A
// fragments via 32-bit byte offsets, no in-loop barriers. nidx for the NEXT
// iteration is prefetched at loop top so the gather chain (nidx -> addr ->
// gather) is off the critical path. Bias deferred from stats (closed form).
__global__ __launch_bounds__(256) void k_gemmA(const f16* __restrict__ xh,
                                               const f16* __restrict__ nfh,
                                               const int* __restrict__ nidx,
                                               const f16* __restrict__ Wt,
                                               const float* __restrict__ bl,
                                               float* __restrict__ stats) {
    __shared__ float redS[128], redQ[128];

    const int tid = threadIdx.x;
    const int wv = tid >> 6;
    const int lane = tid & 63;
    const int quad = lane >> 4;
    const int l16 = lane & 15;
    const int rhalf = wv >> 1;
    const int c0w = (wv & 1) * 64;
    const unsigned q16 = (unsigned)quad * 16u;

    if (tid < 128) { redS[tid] = 0.0f; redQ[tid] = 0.0f; }

    half8 Bf[6][4];
    float bias_[4];
    float ssum[4] = {0, 0, 0, 0}, ssq[4] = {0, 0, 0, 0};
    int niter = 0;
#pragma unroll
    for (int ct = 0; ct < 4; ++ct) {
        int c = c0w + ct * 16 + l16;
        bias_[ct] = bl[c];
#pragma unroll
        for (int kc = 0; kc < 6; ++kc)
            Bf[kc][ct] = *(const half8*)&Wt[c * KPAD + kc * 32 + quad * 8];
    }

    const char* xb = (const char*)xh;
    const char* nb = (const char*)nfh;
    const ushort4 z4 = make_ushort4(0, 0, 0, 0);

    // prefetch first iteration's neighbor indices
    int ng0 = 0, ng1 = 0;
    {
        const int row0 = blockIdx.x * 64 + rhalf * 32 + l16;
        ng0 = nidx[row0];
        ng1 = nidx[row0 + 16];
    }

    for (int rb = blockIdx.x; rb < RB_TOTAL; rb += gridDim.x) {
        // issue next-iter nidx loads NOW (result needed only next iteration)
        const int rbn = rb + gridDim.x;
        int ng0n = 0, ng1n = 0;
        if (rbn < RB_TOTAL) {
            const int rown = rbn * 64 + rhalf * 32 + l16;
            ng0n = nidx[rown];
            ng1n = nidx[rown + 16];
        }

        const int row0 = rb * 64 + rhalf * 32 + l16;
        const int row1 = row0 + 16;
        const unsigned os0 = (unsigned)((unsigned)row0 / 12u) * 128u + q16;
        const unsigned os1 = (unsigned)((unsigned)row1 / 12u) * 128u + q16;
        const unsigned og0 = (unsigned)ng0 * 128u + q16;
        const unsigned og1 = (unsigned)ng1 * 128u + q16;
        const unsigned on0 = (unsigned)row0 * 88u;
        const unsigned on1 = (unsigned)row1 * 88u;

        H8 a0[6], a1[6];
        a0[0].h = *(const half8*)(xb + os0);
        a0[1].h = *(const half8*)(xb + os0 + 64u);
        a0[2].h = *(const half8*)(xb + og0);
        a0[3].h = *(const half8*)(xb + og0 + 64u);
        a0[4].u[0] = *(const ushort4*)(nb + on0 + q16);
        a0[4].u[1] = *(const ushort4*)(nb + on0 + q16 + 8u);
        a0[5].u[0] = z4; a0[5].u[1] = z4;
        if (quad == 0) {
            a0[5].u[0] = *(const ushort4*)(nb + on0 + 64u);
            a0[5].u[1] = *(const ushort4*)(nb + on0 + 72u);
        } else if (quad == 1) {
            a0[5].u[0] = *(const ushort4*)(nb + on0 + 80u);
        }
        a1[0].h = *(const half8*)(xb + os1);
        a1[1].h = *(const half8*)(xb + os1 + 64u);
        a1[2].h = *(const half8*)(xb + og1);
        a1[3].h = *(const half8*)(xb + og1 + 64u);
        a1[4].u[0] = *(const ushort4*)(nb + on1 + q16);
        a1[4].u[1] = *(const ushort4*)(nb + on1 + q16 + 8u);
        a1[5].u[0] = z4; a1[5].u[1] = z4;
        if (quad == 0) {
            a1[5].u[0] = *(const ushort4*)(nb + on1 + 64u);
            a1[5].u[1] = *(const ushort4*)(nb + on1 + 72u);
        } else if (quad == 1) {
            a1[5].u[0] = *(const ushort4*)(nb + on1 + 80u);
        }

        f32x4 acc[2][4];
#pragma unroll
        for (int rf = 0; rf < 2; ++rf)
#pragma unroll
            for (int ct = 0; ct < 4; ++ct) acc[rf][ct] = (f32x4){0, 0, 0, 0};

#pragma unroll
        for (int kc = 0; kc < 6; ++kc) {
#pragma unroll
            for (int ct = 0; ct < 4; ++ct) {
                acc[0][ct] = __builtin_amdgcn_mfma_f32_16x16x32_f16(a0[kc].h, Bf[kc][ct], acc[0][ct], 0, 0, 0);
                acc[1][ct] = __builtin_amdgcn_mfma_f32_16x16x32_f16(a1[kc].h, Bf[kc][ct], acc[1][ct], 0, 0, 0);
            }
        }

        // stats-only epilogue (bias deferred)
#pragma unroll
        for (int rf = 0; rf < 2; ++rf)
#pragma unroll
            for (int ct = 0; ct < 4; ++ct)
#pragma unroll
                for (int e = 0; e < 4; ++e) {
                    float v = acc[rf][ct][e];
                    ssum[ct] += v;
                    ssq[ct] = fmaf(v, v, ssq[ct]);
                }
        ++niter;
        ng0 = ng0n; ng1 = ng1n;
    }

    // fold the deferred bias: sum(v+b) = S + cnt*b ; sum((v+b)^2) = Q + 2bS + cnt*b^2
    const float cnt = 8.0f * (float)niter;   // 8 values per ct per iteration
#pragma unroll
    for (int ct = 0; ct < 4; ++ct) {
        float b = bias_[ct];
        float S = ssum[ct];
        ssq[ct] = ssq[ct] + 2.0f * b * S + cnt * b * b;
        ssum[ct] = S + cnt * b;
    }

    __syncthreads();   // makes redS/redQ zero-init visible
#pragma unroll
    for (int ct = 0; ct < 4; ++ct) {
        float s = ssum[ct], q = ssq[ct];
        s += __shfl_xor(s, 16); s += __shfl_xor(s, 32);
        q += __shfl_xor(q, 16); q += __shfl_xor(q, 32);
        if (quad == 0) {
            atomicAdd(&redS[c0w + ct * 16 + l16], s);
            atomicAdd(&redQ[c0w + ct * 16 + l16], q);
        }
    }
    __syncthreads();
    if (tid < 128) {
        atomicAdd(&stats[tid], redS[tid]);
        atomicAdd(&stats[128 + tid], redQ[tid]);
    }
}

// ---------------- gemmB: recompute gemm + BN1 + sigmoid*softplus + atom-sum --
// Block = 256 thr (4 waves) x 96 rows (8 atoms). Wave w: rows (w>>1)*48..+47
// (4 atoms), cols = tiles {2s,2s+1,4+2s,5+2s} (s=w&1) so filter col c and
// core col c+64 are in the SAME lane. Atom-sum via per-WAVE LDS scratch
// (intra-wave: lgkmcnt-ordered, no barriers in the loop). nidx prefetched
// one iteration ahead.
__global__ __launch_bounds__(256) void k_gemmB(const f16* __restrict__ xh,
                                               const f16* __restrict__ nfh,
                                               const int* __restrict__ nidx,
                                               const f16* __restrict__ Wt,
                                               const float* __restrict__ bl,
                                               const float* __restrict__ g1,
                                               const float* __restrict__ be1,
                                               float* __restrict__ stats,
                                               float* __restrict__ ns) {
    __shared__ float scr[4][12][33];   // [wave][4-row group][col] (+pad)
    __shared__ float rs[64], rq[64];

    const int tid = threadIdx.x;
    const int wv = tid >> 6;
    const int lane = tid & 63;
    const int quad = lane >> 4;
    const int l16 = lane & 15;
    const int rgrp = wv >> 1;          // row group 0/1 (48 rows each)
    const int csel = wv & 1;           // column half of the 64 product cols
    const unsigned q16 = (unsigned)quad * 16u;
    const float cnt1 = (float)N_ATOMS * M_NBR;

    if (tid < 64) { rs[tid] = 0.0f; rq[tid] = 0.0f; }
    __syncthreads();

    const int tmap[4] = {2 * csel, 2 * csel + 1, 4 + 2 * csel, 5 + 2 * csel};
    float P[4], Q[4];
    half8 Bf[4][6];
#pragma unroll
    for (int jt = 0; jt < 4; ++jt) {
        int c = tmap[jt] * 16 + l16;
        float m1 = stats[c] / cnt1;
        float v1 = stats[128 + c] / cnt1 - m1 * m1;
        float A1 = g1[c] * rsqrtf(v1 + BN_EPS);
        P[jt] = A1;
        Q[jt] = fmaf(A1, bl[c], be1[c] - A1 * m1);   // BN1 with gemm-bias folded in
#pragma unroll
        for (int kc = 0; kc < 6; ++kc)
            Bf[jt][kc] = *(const half8*)&Wt[c * KPAD + kc * 32 + quad * 8];
    }

    const char* xb = (const char*)xh;
    const char* nb = (const char*)nfh;
    const ushort4 z4 = make_ushort4(0, 0, 0, 0);
    float ls[2] = {0, 0}, lq2[2] = {0, 0};

    // prefetch first iteration's neighbor indices
    int ng[3];
    {
        const int rw = blockIdx.x * 96 + rgrp * 48;
#pragma unroll
        for (int rt = 0; rt < 3; ++rt) ng[rt] = nidx[rw + rt * 16 + l16];
    }

    for (int bt = blockIdx.x; bt < BT_TOTAL; bt += gridDim.x) {
        // issue next-iter nidx loads NOW
        const int btn = bt + gridDim.x;
        int ngn[3] = {0, 0, 0};
        if (btn < BT_TOTAL) {
            const int rwn = btn * 96 + rgrp * 48;
#pragma unroll
            for (int rt = 0; rt < 3; ++rt) ngn[rt] = nidx[rwn + rt * 16 + l16];
        }

        const int rw = bt * 96 + rgrp * 48;
        float part[3][2];
#pragma unroll
        for (int rt = 0; rt < 3; ++rt) {
            const int r = rw + rt * 16 + l16;
            const unsigned osf = (unsigned)((unsigned)r / 12u) * 128u + q16;
            const unsigned ogf = (unsigned)ng[rt] * 128u + q16;
            const unsigned onf = (unsigned)r * 88u;
            H8 a[6];
            a[0].h = *(const half8*)(xb + osf);
            a[1].h = *(const half8*)(xb + osf + 64u);
            a[2].h = *(const half8*)(xb + ogf);
            a[3].h = *(const half8*)(xb + ogf + 64u);
            a[4].u[0] = *(const ushort4*)(nb + onf + q16);
            a[4].u[1] = *(const ushort4*)(nb + onf + q16 + 8u);
            a[5].u[0] = z4; a[5].u[1] = z4;
            if (quad == 0) {
                a[5].u[0] = *(const ushort4*)(nb + onf + 64u);
                a[5].u[1] = *(const ushort4*)(nb + onf + 72u);
            } else if (quad == 1) {
                a[5].u[0] = *(const ushort4*)(nb + onf + 80u);
            }

            f32x4 acc[4];
#pragma unroll
            for (int jt = 0; jt < 4; ++jt) acc[jt] = (f32x4){0, 0, 0, 0};
#pragma unroll
            for (int kc = 0; kc < 6; ++kc)
#pragma unroll
                for (int jt = 0; jt < 4; ++jt)
                    acc[jt] = __builtin_amdgcn_mfma_f32_16x16x32_f16(a[kc].h, Bf[jt][kc], acc[jt], 0, 0, 0);

            // C layout: row = rw + rt*16 + quad*4 + e, col = tmap[jt]*16 + l16
#pragma unroll
            for (int j = 0; j < 2; ++j) {
                float s = 0.0f;
#pragma unroll
                for (int e = 0; e < 4; ++e) {
                    float vf = fmaf(P[j],     acc[j][e],     Q[j]);       // filter col
                    float vc = fmaf(P[j + 2], acc[j + 2][e], Q[j + 2]);   // core col (+64)
                    s = fmaf(sigmoidf_(vf), softplusf_(vc), s);
                }
                part[rt][j] = s;   // sum over rows of group g = rt*4+quad
            }
        }
        // intra-wave exchange (no barrier): group g partial lives in lane
        // (g&3)*16+l16 of the same wave, register part[g>>2].
#pragma unroll
        for (int rt = 0; rt < 3; ++rt)
#pragma unroll
            for (int j = 0; j < 2; ++j)
                scr[wv][rt * 4 + quad][j * 16 + l16] = part[rt][j];
        // atom a = quad (4 atoms/wave); its 12 rows = groups 3a..3a+2
#pragma unroll
        for (int j = 0; j < 2; ++j) {
            int cj = j * 16 + l16;
            float s = scr[wv][3 * quad][cj] + scr[wv][3 * quad + 1][cj] + scr[wv][3 * quad + 2][cj];
            const int n = bt * 8 + rgrp * 4 + quad;
            ns[(size_t)n * 64 + csel * 32 + cj] = s;
            ls[j] += s;
            lq2[j] = fmaf(s, s, lq2[j]);
        }
        ng[0] = ngn[0]; ng[1] = ngn[1]; ng[2] = ngn[2];
    }

    // BN2 stats: per-lane col fixed (csel*32 + j*16 + l16); quads hold
    // disjoint atoms -> reduce across quads, then across waves via LDS+atomics.
#pragma unroll
    for (int j = 0; j < 2; ++j) {
        float s = ls[j], q = lq2[j];
        s += __shfl_xor(s, 16); s += __shfl_xor(s, 32);
        q += __shfl_xor(q, 16); q += __shfl_xor(q, 32);
        if (quad == 0) {
            atomicAdd(&rs[csel * 32 + j * 16 + l16], s);
            atomicAdd(&rq[csel * 32 + j * 16 + l16], q);
        }
    }
    __syncthreads();
    if (tid < 64) {
        atomicAdd(&stats[256 + tid], rs[tid]);
        atomicAdd(&stats[320 + tid], rq[tid]);
    }
}

// ---------------- convC (vectorized) + prepW(l+1) fused ----------------------
// Blocks [0, 8192): x = softplus(x + BN2(ns)), 4 elems/thread (f32x4).
// Blocks [8192, 8288): prepW for the next layer (gated by do_prep).
// (This fusion is safe -- no LDS, low VGPR, streaming role dominates 8192:96.)
__global__ __launch_bounds__(256) void k_convC2(float* __restrict__ x,
                                                f16* __restrict__ xh,
                                                const float* __restrict__ ns,
                                                const float* __restrict__ g2,
                                                const float* __restrict__ be2,
                                                const float* __restrict__ stats,
                                                const float* __restrict__ Wn,
                                                f16* __restrict__ Wt,
                                                int do_prep) {
    const int tid = threadIdx.x;
    if (blockIdx.x < 8192) {
        const int i4 = blockIdx.x * 256 + tid;       // < N*64/4
        const size_t base = (size_t)i4 * 4;
        const int f0 = (int)(base & 63);
        const float cnt = (float)N_ATOMS;
        f32x4 m4 = *(const f32x4*)&stats[256 + f0];
        f32x4 q4 = *(const f32x4*)&stats[320 + f0];
        f32x4 g4 = *(const f32x4*)&g2[f0];
        f32x4 b4 = *(const f32x4*)&be2[f0];
        f32x4 xv = *(const f32x4*)&x[base];
        f32x4 nv = *(const f32x4*)&ns[base];
        f16 h4[4];
#pragma unroll
        for (int j = 0; j < 4; ++j) {
            float m = m4[j] / cnt;
            float v = q4[j] / cnt - m * m;
            float A = g4[j] * rsqrtf(v + BN_EPS);
            float B = b4[j] - A * m;
            float o = softplusf_(xv[j] + fmaf(A, nv[j], B));
            xv[j] = o;
            h4[j] = (f16)o;
        }
        *(f32x4*)&x[base] = xv;
        *(ushort4*)&xh[base] = *(const ushort4*)h4;
    } else if (do_prep) {
        const int i = (blockIdx.x - 8192) * 256 + tid;
        if (i < C2 * KPAD) {
            int c = i / KPAD, k = i - c * KPAD;
            Wt[i] = (k < FIN) ? (f16)Wn[k * C2 + c] : (f16)0.0f;
        }
    }
}

// ---------------- pool: per-crystal mean (sorted idx, binary search) ---------
__global__ __launch_bounds__(64) void k_pool(const float* __restrict__ x,
                                             const int* __restrict__ cidx,
                                             float* __restrict__ crys) {
    const int s = blockIdx.x;
    const int f = threadIdx.x;
    int lo = 0, hi = N_ATOMS;
    while (lo < hi) { int mid = (lo + hi) >> 1; if (cidx[mid] < s) lo = mid + 1; else hi = mid; }
    int lo2 = lo, hi2 = N_ATOMS;
    while (lo2 < hi2) { int mid = (lo2 + hi2) >> 1; if (cidx[mid] < s + 1) lo2 = mid + 1; else hi2 = mid; }
    float sum = 0.0f;
    for (int i = lo; i < lo2; ++i) sum += x[(size_t)i * 64 + f];
    float cnt = fmaxf((float)(lo2 - lo), 1.0f);
    crys[s * 64 + f] = sum / cnt;
}

// ---------------- head ----------------
__global__ __launch_bounds__(128) void k_head(const float* __restrict__ crys,
                                              const float* __restrict__ W1,
                                              const float* __restrict__ b1,
                                              const float* __restrict__ W2,
                                              const float* __restrict__ b2,
                                              float* __restrict__ out) {
    __shared__ float a_sh[64];
    __shared__ float r_sh[128];
    const int n = blockIdx.x;
    const int tid = threadIdx.x;
    if (tid < 64) a_sh[tid] = softplusf_(crys[n * 64 + tid]);
    __syncthreads();
    for (int p = 0; p < 2; ++p) {
        float acc = b1[p * 128 + tid];
#pragma unroll
        for (int f2 = 0; f2 < 64; ++f2)
            acc = fmaf(a_sh[f2], W1[(p * 64 + f2) * 128 + tid], acc);
        float contrib = softplusf_(acc) * W2[p * 128 + tid];
        r_sh[tid] = contrib;
        __syncthreads();
        for (int sft = 64; sft > 0; sft >>= 1) {
            if (tid < sft) r_sh[tid] += r_sh[tid + sft];
            __syncthreads();
        }
        if (tid == 0) out[n * 2 + p] = r_sh[0] + b2[p];
        __syncthreads();
    }
}

extern "C" void kernel_launch(void* const* d_in, const int* in_sizes, int n_in,
                              void* d_out, int out_size, void* d_ws, size_t ws_size,
                              hipStream_t stream) {
    const float* atom_fea = (const float*)d_in[0];
    const float* nbr_fea  = (const float*)d_in[1];
    const float* W_embed  = (const float*)d_in[2];
    const float* b_embed  = (const float*)d_in[3];
    const float* conv_W   = (const float*)d_in[4];
    const float* conv_b   = (const float*)d_in[5];
    const float* conv_g1  = (const float*)d_in[6];
    const float* conv_be1 = (const float*)d_in[7];
    const float* conv_g2  = (const float*)d_in[8];
    const float* conv_be2 = (const float*)d_in[9];
    const float* head_W1  = (const float*)d_in[10];
    const float* head_b1  = (const float*)d_in[11];
    const float* head_W2  = (const float*)d_in[12];
    const float* head_b2  = (const float*)d_in[13];
    const int*   nidx     = (const int*)d_in[14];
    const int*   cryst    = (const int*)d_in[15];

    // workspace layout (nfh 44-f16 stride)
    char* w = (char*)d_ws;
    float* x      = (float*)w;                        //  33,554,432
    f16*   xh     = (f16*)(w + 33554432);             //  16,777,216
    float* ns     = (float*)(w + 50331648);           //  33,554,432
    f16*   nfh    = (f16*)(w + 83886080);             // 138,412,032
    f16*   Wt     = (f16*)(w + 222298112);            //      49,152
    float* stats  = (float*)(w + 222347264);          //       4,608
    const size_t required = 222347264ull + 4608ull;
    if (ws_size < required) {
        hipMemsetAsync(d_out, 0x7F, 4, stream);
        return;
    }

    hipMemsetAsync(stats, 0, NCONV * 384 * sizeof(float), stream);

    k_cvt_nbrf<<<N_ATOMS * M_NBR / 32, 256, 0, stream>>>(nbr_fea, nfh);
    k_embed<<<N_ATOMS / 128, 256, 0, stream>>>(atom_fea, W_embed, b_embed, x, xh);
    k_prepW<<<(C2 * KPAD + 255) / 256, 256, 0, stream>>>(conv_W, Wt);

    for (int l = 0; l < NCONV; ++l) {
        float* st = stats + l * 384;
        k_gemmA<<<2048, 256, 0, stream>>>(xh, nfh, nidx, Wt, conv_b + l * C2, st);
        k_gemmB<<<2048, 256, 0, stream>>>(xh, nfh, nidx, Wt, conv_b + l * C2,
                                          conv_g1 + l * C2, conv_be1 + l * C2, st, ns);
        const int ln = (l + 1 < NCONV) ? l + 1 : l;
        k_convC2<<<8288, 256, 0, stream>>>(x, xh, ns, conv_g2 + l * AF, conv_be2 + l * AF, st,
                                           conv_W + (size_t)ln * FIN * C2, Wt, (l + 1 < NCONV) ? 1 : 0);
    }

    float* crys = (float*)d_out + N0_CRYS * 2;   // crys_fea follows out
    k_pool<<<N0_CRYS, 64, 0, stream>>>(x, cryst, crys);
    k_head<<<N0_CRYS, 128, 0, stream>>>(crys, head_W1, head_b1, head_W2, head_b2, (float*)d_out);
}